// Round 8
// baseline (465.341 us; speedup 1.0000x reference)
//
#include <hip/hip_runtime.h>
#include <hip/hip_cooperative_groups.h>

namespace cg = cooperative_groups;

// EMA energy normalizer: mag [B,F,T] fp32 -> (mag_norm [B,F,T], mag_mean [B,1,T])
//
// R10 (resubmit — R7 bench was a broker timeout, no data): single COOPERATIVE
// kernel — replace kernel-boundary drains with two grid.sync()s.
// Evidence trail:
//  - R7 (3-kernel) = 206us, R9 (2-kernel, redundant scan) = 207us -> scan
//    structure worth ~0; slack is launch gaps + drains + streaming.
//  - Fills (harness re-poison) = 2x58us immovable; ours ~= 90us.
//  - R8's one-pass failed from register SPILL (VGPR=76, r[8][3] -> scratch)
//    + hand-rolled spin storms; this design holds nothing across phases and
//    uses the runtime grid barrier instead of hand spins.
//  - ws >= 12.7MB proven available (R8's path executed).
// Phases: A) 1024 blocks reduce 8-9 own rows -> partial[b][ch] (linear IO)
//         B) 32 blocks: 32 partials -> frame means -> affine Hillis-Steele
//            scan (validated R5/R7/R9) -> mag_mean + recip
//         C) all blocks: recip row (12KB, L2) -> stream-normalize own rows.
// Fallback: proven R9 two-kernel pipeline if coop launch unavailable/fails.

#define B_   32
#define F_   257
#define T_   3000
#define T4   750          // float4s per row
#define NCH  32           // chunks (blocks) per batch in coop kernel
#define MOM  0.99f
#define OMM  0.01f
#define EPS_ 1e-8f
#define INVF (1.0f / 257.0f)

#define ACC4(a, v) { a.x += v.x; a.y += v.y; a.z += v.z; a.w += v.w; }

// ---------------------------------------------------------------------------
// R10 cooperative kernel. Grid = B_*NCH = 1024 blocks, 256 thr, <=4 blk/CU.
// ---------------------------------------------------------------------------
__global__ __launch_bounds__(256, 4) void ema_coop(
    const float* __restrict__ mag,
    const float* __restrict__ bias,
    const float* __restrict__ rmean,
    float* __restrict__ out,
    float* __restrict__ mag_mean,
    float* __restrict__ partial,       // [B_][NCH][T_]
    float* __restrict__ recip)         // [B_][T_]
{
    __shared__ float4 xs4[T4];         // 12 KB (phase B only)
    float* xs = reinterpret_cast<float*>(xs4);
    __shared__ float sA[256];
    __shared__ float sB[256];

    cg::grid_group grid = cg::this_grid();

    const int blk = blockIdx.x;        // b*NCH + ch
    const int b   = blk >> 5;
    const int ch  = blk & (NCH - 1);
    const int tid = threadIdx.x;
    const bool c2 = tid < (T4 - 512);  // tid < 238 owns a third float4 column

    const float4* magv = reinterpret_cast<const float4*>(mag)
                       + (size_t)(b * F_ + ch * 8) * T4;
    const int nr = (ch == NCH - 1) ? 9 : 8;   // ch 31 also owns row 256

    // ---- phase A: reduce own rows (fully linear reads), write partial row
    {
        float4 a0 = make_float4(0.f,0.f,0.f,0.f);
        float4 a1 = make_float4(0.f,0.f,0.f,0.f);
        float4 a2 = make_float4(0.f,0.f,0.f,0.f);
        for (int r = 0; r < nr; ++r) {
            const float4* row = magv + (size_t)r * T4;
            float4 v0 = row[tid];
            float4 v1 = row[tid + 256];
            ACC4(a0, v0);
            ACC4(a1, v1);
            if (c2) { float4 v2 = row[tid + 512]; ACC4(a2, v2); }
        }
        float4* pv = reinterpret_cast<float4*>(partial) + (size_t)blk * T4;
        pv[tid]       = a0;
        pv[tid + 256] = a1;
        if (c2) pv[tid + 512] = a2;
    }
    __threadfence();                   // release: partials visible device-wide
    grid.sync();

    // ---- phase B: 32 scan blocks (b = blk); others pass through to sync
    if (blk < B_) {
        const int sb = blk;            // batch this scan block owns
        const float4* pv = reinterpret_cast<const float4*>(partial)
                         + (size_t)sb * NCH * T4;
        float4 s0 = make_float4(0.f,0.f,0.f,0.f);
        float4 s1 = make_float4(0.f,0.f,0.f,0.f);
        float4 s2 = make_float4(0.f,0.f,0.f,0.f);
        #pragma unroll 4
        for (int r = 0; r < NCH; ++r) {
            const float4* rp = pv + (size_t)r * T4;
            float4 v0 = rp[tid];
            float4 v1 = rp[tid + 256];
            ACC4(s0, v0);
            ACC4(s1, v1);
            if (c2) { float4 v2 = rp[tid + 512]; ACC4(s2, v2); }
        }
        s0.x *= INVF; s0.y *= INVF; s0.z *= INVF; s0.w *= INVF;
        s1.x *= INVF; s1.y *= INVF; s1.z *= INVF; s1.w *= INVF;
        xs4[tid]       = s0;
        xs4[tid + 256] = s1;
        if (c2) {
            s2.x *= INVF; s2.y *= INVF; s2.z *= INVF; s2.w *= INVF;
            xs4[tid + 512] = s2;
        }
        __syncthreads();

        // local chunk scan: 250 active threads x 12 steps (validated)
        const int CH = 12;
        const int t0 = tid * CH;
        float A = 1.f, Bv = 0.f;
        if (t0 < T_) {
            #pragma unroll
            for (int j = 0; j < CH; ++j) {
                Bv = MOM * Bv + OMM * xs[t0 + j];
                A *= MOM;
            }
        }
        sA[tid] = A; sB[tid] = Bv;
        __syncthreads();

        // Hillis-Steele over affine maps: (Ap,Bp)∘(Ac,Bc) = (Ap*Ac, Bp*Ac+Bc)
        for (int off = 1; off < 256; off <<= 1) {
            float cA = sA[tid], cB = sB[tid];
            float pA = 1.f, pB = 0.f;
            if (tid >= off) { pA = sA[tid - off]; pB = sB[tid - off]; }
            __syncthreads();
            if (tid >= off) { sA[tid] = pA * cA; sB[tid] = pB * cA + cB; }
            __syncthreads();
        }
        float pA = 1.f, pB = 0.f;
        if (tid > 0) { pA = sA[tid - 1]; pB = sB[tid - 1]; }
        __syncthreads();

        const float bias0 = bias[0];
        if (t0 < T_) {
            float m = pA * rmean[0] + pB;        // m_{t0-1}
            #pragma unroll
            for (int j = 0; j < CH; ++j) {
                m = MOM * m + OMM * xs[t0 + j];
                xs[t0 + j] = m + bias0;          // mean + bias
            }
        }
        __syncthreads();

        // emit mag_mean and recip table (linear 12 KB writes)
        float4* mmv = reinterpret_cast<float4*>(mag_mean) + (size_t)sb * T4;
        float4* rcv = reinterpret_cast<float4*>(recip)    + (size_t)sb * T4;
        for (int i = tid; i < T4; i += 256) {
            float4 v = xs4[i];
            mmv[i] = v;
            float4 rv;
            rv.x = 1.0f / (v.x + EPS_); rv.y = 1.0f / (v.y + EPS_);
            rv.z = 1.0f / (v.z + EPS_); rv.w = 1.0f / (v.w + EPS_);
            rcv[i] = rv;
        }
        __threadfence();               // release: recip visible device-wide
    }
    grid.sync();

    // ---- phase C: all blocks normalize own rows from recip (L2-hot, 12 KB)
    const float4* rcv = reinterpret_cast<const float4*>(recip) + (size_t)b * T4;
    const float4 r0 = rcv[tid];
    const float4 r1 = rcv[tid + 256];
    const float4 r2 = c2 ? rcv[tid + 512] : r0;

    float4* ov = reinterpret_cast<float4*>(out) + (size_t)(b * F_ + ch * 8) * T4;
    for (int r = 0; r < nr; ++r) {
        const float4* row  = magv + (size_t)r * T4;
        float4*       orow = ov   + (size_t)r * T4;
        float4 v0 = row[tid];
        float4 v1 = row[tid + 256];
        float4 o;
        o.x = v0.x * r0.x; o.y = v0.y * r0.y; o.z = v0.z * r0.z; o.w = v0.w * r0.w;
        orow[tid] = o;
        o.x = v1.x * r1.x; o.y = v1.y * r1.y; o.z = v1.z * r1.z; o.w = v1.w * r1.w;
        orow[tid + 256] = o;
        if (c2) {
            float4 v2 = row[tid + 512];
            o.x = v2.x * r2.x; o.y = v2.y * r2.y; o.z = v2.z * r2.z; o.w = v2.w * r2.w;
            orow[tid + 512] = o;
        }
    }
}

// ===========================================================================
// Fallback: proven R9 two-kernel pipeline (207us).
// ===========================================================================
#define NG1  16

__global__ __launch_bounds__(256) void k1_partial(const float* __restrict__ mag,
                                                  float* __restrict__ partial) {
    const int blk = blockIdx.x;          // b*16 + g
    const int b   = blk >> 4;
    const int g   = blk & 15;
    const int tid = threadIdx.x;
    const bool has2 = tid < (T4 - 512);

    const float4* magv = reinterpret_cast<const float4*>(mag)
                       + ((size_t)(b * F_ + g * 16)) * T4;
    float4 a0 = make_float4(0.f,0.f,0.f,0.f);
    float4 a1 = make_float4(0.f,0.f,0.f,0.f);
    float4 a2 = make_float4(0.f,0.f,0.f,0.f);

    #pragma unroll 4
    for (int r = 0; r < 16; ++r) {
        const float4* row = magv + (size_t)r * T4;
        float4 v0 = row[tid];
        float4 v1 = row[tid + 256];
        ACC4(a0, v0); ACC4(a1, v1);
        if (has2) { float4 v2 = row[tid + 512]; ACC4(a2, v2); }
    }
    if (g == 15) {
        const float4* row = magv + (size_t)16 * T4;
        float4 v0 = row[tid];
        float4 v1 = row[tid + 256];
        ACC4(a0, v0); ACC4(a1, v1);
        if (has2) { float4 v2 = row[tid + 512]; ACC4(a2, v2); }
    }
    float4* pv = reinterpret_cast<float4*>(partial) + (size_t)blk * T4;
    pv[tid]       = a0;
    pv[tid + 256] = a1;
    if (has2) pv[tid + 512] = a2;
}

__global__ __launch_bounds__(256) void k2_scan_norm(
    const float* __restrict__ partial,
    const float* __restrict__ bias,
    const float* __restrict__ rmean,
    const float* __restrict__ mag,
    float* __restrict__ out,
    float* __restrict__ mag_mean)
{
    __shared__ float4 xs4[T4];
    float* xs = reinterpret_cast<float*>(xs4);
    __shared__ float sA[256];
    __shared__ float sB[256];

    const int blk = blockIdx.x;          // b*33 + ch
    const int b   = blk / 33;
    const int ch  = blk % 33;
    const int tid = threadIdx.x;
    const bool c2 = tid < (T4 - 512);

    {
        const float4* pv = reinterpret_cast<const float4*>(partial)
                         + (size_t)b * NG1 * T4;
        float4 s0 = make_float4(0.f,0.f,0.f,0.f);
        float4 s1 = make_float4(0.f,0.f,0.f,0.f);
        float4 s2 = make_float4(0.f,0.f,0.f,0.f);
        #pragma unroll 4
        for (int r = 0; r < NG1; ++r) {
            const float4* rp = pv + (size_t)r * T4;
            float4 v0 = rp[tid];
            float4 v1 = rp[tid + 256];
            ACC4(s0, v0); ACC4(s1, v1);
            if (c2) { float4 v2 = rp[tid + 512]; ACC4(s2, v2); }
        }
        s0.x *= INVF; s0.y *= INVF; s0.z *= INVF; s0.w *= INVF;
        s1.x *= INVF; s1.y *= INVF; s1.z *= INVF; s1.w *= INVF;
        xs4[tid]       = s0;
        xs4[tid + 256] = s1;
        if (c2) {
            s2.x *= INVF; s2.y *= INVF; s2.z *= INVF; s2.w *= INVF;
            xs4[tid + 512] = s2;
        }
    }
    __syncthreads();

    const int CH = 12;
    const int t0 = tid * CH;
    float A = 1.f, Bv = 0.f;
    if (t0 < T_) {
        #pragma unroll
        for (int j = 0; j < CH; ++j) {
            Bv = MOM * Bv + OMM * xs[t0 + j];
            A *= MOM;
        }
    }
    sA[tid] = A; sB[tid] = Bv;
    __syncthreads();

    for (int off = 1; off < 256; off <<= 1) {
        float cA = sA[tid], cB = sB[tid];
        float pA = 1.f, pB = 0.f;
        if (tid >= off) { pA = sA[tid - off]; pB = sB[tid - off]; }
        __syncthreads();
        if (tid >= off) { sA[tid] = pA * cA; sB[tid] = pB * cA + cB; }
        __syncthreads();
    }
    float pA = 1.f, pB = 0.f;
    if (tid > 0) { pA = sA[tid - 1]; pB = sB[tid - 1]; }
    __syncthreads();

    const float bias0 = bias[0];
    if (t0 < T_) {
        float m = pA * rmean[0] + pB;
        #pragma unroll
        for (int j = 0; j < CH; ++j) {
            m = MOM * m + OMM * xs[t0 + j];
            xs[t0 + j] = m + bias0;
        }
    }
    __syncthreads();

    if (ch == 0) {
        float4* mmv = reinterpret_cast<float4*>(mag_mean) + (size_t)b * T4;
        for (int i = tid; i < T4; i += 256) mmv[i] = xs4[i];
    }
    for (int i = tid; i < T4; i += 256) {
        float4 v = xs4[i];
        v.x = 1.0f / (v.x + EPS_); v.y = 1.0f / (v.y + EPS_);
        v.z = 1.0f / (v.z + EPS_); v.w = 1.0f / (v.w + EPS_);
        xs4[i] = v;
    }
    __syncthreads();

    const float4 r0 = xs4[tid];
    const float4 r1 = xs4[tid + 256];
    const float4 r2 = c2 ? xs4[tid + 512] : r0;

    const int f0 = ch * 8;
    const int nr = (ch == 32) ? 1 : 8;
    const float4* magv = reinterpret_cast<const float4*>(mag)
                       + ((size_t)(b * F_ + f0)) * T4;
    float4* ov = reinterpret_cast<float4*>(out)
               + ((size_t)(b * F_ + f0)) * T4;

    for (int r = 0; r < nr; ++r) {
        const float4* row  = magv + (size_t)r * T4;
        float4*       orow = ov   + (size_t)r * T4;
        float4 v0 = row[tid];
        float4 v1 = row[tid + 256];
        float4 o;
        o.x = v0.x * r0.x; o.y = v0.y * r0.y; o.z = v0.z * r0.z; o.w = v0.w * r0.w;
        orow[tid] = o;
        o.x = v1.x * r1.x; o.y = v1.y * r1.y; o.z = v1.z * r1.z; o.w = v1.w * r1.w;
        orow[tid + 256] = o;
        if (c2) {
            float4 v2 = row[tid + 512];
            o.x = v2.x * r2.x; o.y = v2.y * r2.y; o.z = v2.z * r2.z; o.w = v2.w * r2.w;
            orow[tid + 512] = o;
        }
    }
}

extern "C" void kernel_launch(void* const* d_in, const int* in_sizes, int n_in,
                              void* d_out, int out_size, void* d_ws, size_t ws_size,
                              hipStream_t stream) {
    (void)in_sizes; (void)n_in; (void)out_size;
    const float* mag   = (const float*)d_in[0];
    const float* bias  = (const float*)d_in[1];
    const float* rmean = (const float*)d_in[2];
    float* out      = (float*)d_out;
    float* mag_mean = out + (size_t)B_ * F_ * T_;       // second tuple output

    const size_t coop_partial = (size_t)B_ * NCH * T_;  // 3,072,000 floats
    const size_t coop_recip   = (size_t)B_ * T_;
    const size_t need_coop    = (coop_partial + coop_recip) * sizeof(float); // 12.68 MB

    // cooperative-launch capability (host-side query; capture-safe)
    static int coop_ok = -1;
    if (coop_ok < 0) {
        int dev = 0, val = 0;
        hipGetDevice(&dev);
        hipDeviceGetAttribute(&val, hipDeviceAttributeCooperativeLaunch, dev);
        coop_ok = val ? 1 : 0;
    }

    if (coop_ok == 1 && ws_size >= need_coop) {
        float* partial = (float*)d_ws;
        float* recip   = partial + coop_partial;
        void* args[] = { (void*)&mag, (void*)&bias, (void*)&rmean,
                         (void*)&out, (void*)&mag_mean,
                         (void*)&partial, (void*)&recip };
        hipError_t e = hipLaunchCooperativeKernel((const void*)ema_coop,
                                                  dim3(B_ * NCH), dim3(256),
                                                  args, 0, stream);
        if (e == hipSuccess) return;
        coop_ok = 0;                   // don't retry a failing path
    }

    // fallback: proven R9 two-kernel pipeline
    const size_t partial_sz = (size_t)B_ * NG1 * T_ * sizeof(float);  // 6.14 MB
    float* partial = (float*)d_ws;
    k1_partial<<<B_ * NG1, 256, 0, stream>>>(mag, partial);
    k2_scan_norm<<<B_ * 33, 256, 0, stream>>>(partial, bias, rmean, mag,
                                              out, mag_mean);
    (void)partial_sz;
}

// Round 9
// 202.028 us; speedup vs baseline: 2.3034x; 2.3034x over previous
//
#include <hip/hip_runtime.h>

// EMA energy normalizer: mag [B,F,T] fp32 -> (mag_norm [B,F,T], mag_mean [B,1,T])
//
// R11: R9's proven flagless 2-kernel pipeline, tail- and prologue-trimmed.
// Evidence trail:
//  - R7 (3-kernel) 206us == R9 (2-kernel) 207us: scan structure worth ~0.
//  - R10 (cooperative, linear, perfect traffic) = 335us with VALUBusy 0.8%:
//    ~280us in two grid.sync()s -> grid-wide spin barriers cost ~100-150us
//    each on this part (agent-scope acquire spin = cross-XCD invalidate
//    storm; R6=352, R8=510 corroborate). Kernel boundaries ARE the cheap sync.
//  - R9 slack vs ideal (~85 vs ~50us): k2's 1056-block grid = 4.125
//    block-waves/CU (straggler wave pays full 192KB prologue for 1 row) and
//    a 16-row prologue where 8 suffice.
// R11 changes (structure unchanged, both kernels proven code):
//  - K1: 256 blocks (b,g<8), 32-33 rows each -> 8 partial rows/batch.
//  - K2: EXACTLY 1024 blocks (4/CU, one co-resident wave); ch<31 -> 8 rows,
//    ch==31 -> 9 rows (248..256). Prologue reads 8 partial rows (96KB).

#define B_   32
#define F_   257
#define T_   3000
#define T4   750          // float4s per row
#define NG1  8            // partial rows per batch; g==7 folds row 256
#define MOM  0.99f
#define OMM  0.01f
#define EPS_ 1e-8f
#define INVF (1.0f / 257.0f)

#define ACC4(a, v) { a.x += v.x; a.y += v.y; a.z += v.z; a.w += v.w; }

// ---------------------------------------------------------------------------
// K1: block (b, g<8) reduces rows [g*32, g*32+32) (g==7: +row 256) of batch b
// into one partial row. Fully linear 1KB-per-wave reads. 256 blocks = 1/CU.
// ---------------------------------------------------------------------------
__global__ __launch_bounds__(256) void k1_partial(const float* __restrict__ mag,
                                                  float* __restrict__ partial) {
    const int blk = blockIdx.x;          // b*8 + g
    const int b   = blk >> 3;
    const int g   = blk & 7;
    const int tid = threadIdx.x;
    const bool has2 = tid < (T4 - 512);  // tid < 238 owns a third column

    const float4* magv = reinterpret_cast<const float4*>(mag)
                       + ((size_t)(b * F_ + g * 32)) * T4;
    float4 a0 = make_float4(0.f,0.f,0.f,0.f);
    float4 a1 = make_float4(0.f,0.f,0.f,0.f);
    float4 a2 = make_float4(0.f,0.f,0.f,0.f);

    #pragma unroll 4
    for (int r = 0; r < 32; ++r) {
        const float4* row = magv + (size_t)r * T4;
        float4 v0 = row[tid];
        float4 v1 = row[tid + 256];
        ACC4(a0, v0);
        ACC4(a1, v1);
        if (has2) { float4 v2 = row[tid + 512]; ACC4(a2, v2); }
    }
    if (g == 7) {                        // row 256 (the odd one out)
        const float4* row = magv + (size_t)32 * T4;
        float4 v0 = row[tid];
        float4 v1 = row[tid + 256];
        ACC4(a0, v0);
        ACC4(a1, v1);
        if (has2) { float4 v2 = row[tid + 512]; ACC4(a2, v2); }
    }

    float4* pv = reinterpret_cast<float4*>(partial) + (size_t)blk * T4;
    pv[tid]       = a0;
    pv[tid + 256] = a1;
    if (has2) pv[tid + 512] = a2;
}

// ---------------------------------------------------------------------------
// K2: block (b, ch<32) — per-block {reduce 8 partials (96KB, L2/L3) + affine
// scan}, then stream-normalize rows [ch*8, ch*8+nr), nr=8 (+1 for ch==31).
// Grid = 1024 = exactly 4 blocks/CU: single co-resident wave, no straggler.
// ---------------------------------------------------------------------------
__global__ __launch_bounds__(256) void k2_scan_norm(
    const float* __restrict__ partial,
    const float* __restrict__ bias,
    const float* __restrict__ rmean,
    const float* __restrict__ mag,
    float* __restrict__ out,
    float* __restrict__ mag_mean)
{
    __shared__ float4 xs4[T4];           // 12 KB: means -> mean+bias -> recips
    float* xs = reinterpret_cast<float*>(xs4);
    __shared__ float sA[256];
    __shared__ float sB[256];

    const int blk = blockIdx.x;          // b*32 + ch
    const int b   = blk >> 5;
    const int ch  = blk & 31;
    const int tid = threadIdx.x;
    const bool c2 = tid < (T4 - 512);

    // ---- reduce the 8 partial rows (96 KB, L2/L3-resident) -> frame means
    {
        const float4* pv = reinterpret_cast<const float4*>(partial)
                         + (size_t)b * NG1 * T4;
        float4 s0 = make_float4(0.f,0.f,0.f,0.f);
        float4 s1 = make_float4(0.f,0.f,0.f,0.f);
        float4 s2 = make_float4(0.f,0.f,0.f,0.f);
        #pragma unroll
        for (int r = 0; r < NG1; ++r) {
            const float4* rp = pv + (size_t)r * T4;
            float4 v0 = rp[tid];
            float4 v1 = rp[tid + 256];
            ACC4(s0, v0);
            ACC4(s1, v1);
            if (c2) { float4 v2 = rp[tid + 512]; ACC4(s2, v2); }
        }
        s0.x *= INVF; s0.y *= INVF; s0.z *= INVF; s0.w *= INVF;
        s1.x *= INVF; s1.y *= INVF; s1.z *= INVF; s1.w *= INVF;
        xs4[tid]       = s0;
        xs4[tid + 256] = s1;
        if (c2) {
            s2.x *= INVF; s2.y *= INVF; s2.z *= INVF; s2.w *= INVF;
            xs4[tid + 512] = s2;
        }
    }
    __syncthreads();

    // ---- local chunk scan: 250 active threads x 12 steps (validated)
    const int CH = 12;
    const int t0 = tid * CH;
    float A = 1.f, Bv = 0.f;
    if (t0 < T_) {
        #pragma unroll
        for (int j = 0; j < CH; ++j) {
            Bv = MOM * Bv + OMM * xs[t0 + j];
            A *= MOM;
        }
    }
    sA[tid] = A; sB[tid] = Bv;
    __syncthreads();

    // Hillis-Steele over affine maps: (Ap,Bp)∘(Ac,Bc) = (Ap*Ac, Bp*Ac+Bc)
    for (int off = 1; off < 256; off <<= 1) {
        float cA = sA[tid], cB = sB[tid];
        float pA = 1.f, pB = 0.f;
        if (tid >= off) { pA = sA[tid - off]; pB = sB[tid - off]; }
        __syncthreads();
        if (tid >= off) { sA[tid] = pA * cA; sB[tid] = pB * cA + cB; }
        __syncthreads();
    }
    float pA = 1.f, pB = 0.f;
    if (tid > 0) { pA = sA[tid - 1]; pB = sB[tid - 1]; }
    __syncthreads();

    const float bias0 = bias[0];
    if (t0 < T_) {
        float m = pA * rmean[0] + pB;        // m_{t0-1}
        #pragma unroll
        for (int j = 0; j < CH; ++j) {
            m = MOM * m + OMM * xs[t0 + j];
            xs[t0 + j] = m + bias0;          // mean + bias
        }
    }
    __syncthreads();

    // ---- ch==0 emits mag_mean; everyone flips xs to reciprocals
    if (ch == 0) {
        float4* mmv = reinterpret_cast<float4*>(mag_mean) + (size_t)b * T4;
        for (int i = tid; i < T4; i += 256) mmv[i] = xs4[i];
    }
    for (int i = tid; i < T4; i += 256) {
        float4 v = xs4[i];
        v.x = 1.0f / (v.x + EPS_); v.y = 1.0f / (v.y + EPS_);
        v.z = 1.0f / (v.z + EPS_); v.w = 1.0f / (v.w + EPS_);
        xs4[i] = v;
    }
    __syncthreads();

    // ---- stream-normalize rows [f0, f0+nr): recips in registers, linear IO
    const float4 r0 = xs4[tid];
    const float4 r1 = xs4[tid + 256];
    const float4 r2 = c2 ? xs4[tid + 512] : r0;

    const int f0 = ch * 8;
    const int nr = (ch == 31) ? 9 : 8;   // ch31: rows 248..256 inclusive
    const float4* magv = reinterpret_cast<const float4*>(mag)
                       + ((size_t)(b * F_ + f0)) * T4;
    float4* ov = reinterpret_cast<float4*>(out)
               + ((size_t)(b * F_ + f0)) * T4;

    for (int r = 0; r < nr; ++r) {
        const float4* row  = magv + (size_t)r * T4;
        float4*       orow = ov   + (size_t)r * T4;
        float4 v0 = row[tid];
        float4 v1 = row[tid + 256];
        float4 o;
        o.x = v0.x * r0.x; o.y = v0.y * r0.y; o.z = v0.z * r0.z; o.w = v0.w * r0.w;
        orow[tid] = o;
        o.x = v1.x * r1.x; o.y = v1.y * r1.y; o.z = v1.z * r1.z; o.w = v1.w * r1.w;
        orow[tid + 256] = o;
        if (c2) {
            float4 v2 = row[tid + 512];
            o.x = v2.x * r2.x; o.y = v2.y * r2.y; o.z = v2.z * r2.z; o.w = v2.w * r2.w;
            orow[tid + 512] = o;
        }
    }
}

extern "C" void kernel_launch(void* const* d_in, const int* in_sizes, int n_in,
                              void* d_out, int out_size, void* d_ws, size_t ws_size,
                              hipStream_t stream) {
    (void)in_sizes; (void)n_in; (void)out_size; (void)ws_size;
    const float* mag   = (const float*)d_in[0];
    const float* bias  = (const float*)d_in[1];
    const float* rmean = (const float*)d_in[2];
    float* out      = (float*)d_out;
    float* mag_mean = out + (size_t)B_ * F_ * T_;       // second tuple output

    // ws need: B_*NG1*T_ floats = 3.07 MB (ws >= 6.5 MB proven available R7/R9)
    float* partial = (float*)d_ws;
    k1_partial<<<B_ * NG1, 256, 0, stream>>>(mag, partial);
    k2_scan_norm<<<B_ * 32, 256, 0, stream>>>(partial, bias, rmean, mag,
                                              out, mag_mean);
}